// Round 7
// baseline (3506.908 us; speedup 1.0000x reference)
//
#include <hip/hip_runtime.h>
#include <hip/hip_bf16.h>
#include <cstdint>

typedef unsigned int u32;
typedef unsigned short u16;
typedef __bf16 bf16x8 __attribute__((ext_vector_type(8)));
typedef float f32x4 __attribute__((ext_vector_type(4)));
typedef u16 u16x8 __attribute__((ext_vector_type(8)));
typedef u16 u16x4 __attribute__((ext_vector_type(4)));
typedef u32 u32x4 __attribute__((ext_vector_type(4)));

#define T_STEPS 512
#define NGRP 4            // batch groups (16 batches each)
#define GQ 4              // blocks per (layer,group); each owns 64 h-dims
#define HR 4              // h ring slots
#define XR 32             // hs0 ring slots (backpressure keeps lead <= 28)
#define HSLOT (64 * 256)  // u32 per h slot [64 batch][256 dim]
#define XSLOT (64 * 256)

#define FHS_OFF 0u                      // 64 token lines x 16 u32
#define PROG_OFF (16u * 1024u)
#define RING_BYTES (HR * HSLOT * 4)     // 256 KB
#define HA0_OFF (64u * 1024u)
#define HA1_OFF (HA0_OFF + RING_BYTES)
#define HF0_OFF (HA1_OFF + RING_BYTES)
#define HF1_OFF (HF0_OFF + RING_BYTES)
#define XRING_BYTES (XR * XSLOT * 4)    // 2 MB
#define XA_OFF (2u << 20)
#define XF_OFF (XA_OFF + XRING_BYTES)
#define WS_NEEDED (XF_OFF + XRING_BYTES)

__device__ __forceinline__ float sigm(float z) { return 1.f / (1.f + __expf(-z)); }
__device__ __forceinline__ float tanh_(float z) { return 1.f - 2.f / (__expf(2.f * z) + 1.f); }
__device__ __forceinline__ u16 f2bf(float f) {
    union { __bf16 b; u16 u; } v; v.b = (__bf16)f; return v.u;
}
// Agent scope: coherent via MALL (any placement), slow legs.
__device__ __forceinline__ u32 gload(const u32* p) {
    return __hip_atomic_load(p, __ATOMIC_RELAXED, __HIP_MEMORY_SCOPE_AGENT);
}
__device__ __forceinline__ void gstore(u32* p, u32 v) {
    __hip_atomic_store(p, v, __ATOMIC_RELAXED, __HIP_MEMORY_SCOPE_AGENT);
}
// Fast read: RMW (add 0) executes at the issuing XCD's TCC (L2).
__device__ __forceinline__ u32 l2rmw(u32* p) {
    return __hip_atomic_fetch_add(p, 0u, __ATOMIC_RELAXED, __HIP_MEMORY_SCOPE_WORKGROUP);
}
// Fast publish: normal store, write-through L1 -> local TCC.
__device__ __forceinline__ void fpub(u32* p, u32 v) { *(volatile u32*)p = v; }

// Block (grp, layer, q): batches [16*grp..+16), h-dims [64*q..+64).
// 512 threads = 8 waves; wave w owns dims [8w..8w+8) x 4 gates (two n-tiles).
// Tagged words: bf16(h) | step<<16 — arrival IS notification, per-word atomic.
// Every value is published to BOTH a fast ring (local-L2) and an agent ring
// (MALL); readers use fast ring only while it demonstrably works (sticky).
template <int KX, bool L0>
__device__ void lstm_body(
    int grp, int q,
    const float* __restrict__ xf,
    const float* __restrict__ W,    // [1024][256+KX] f32 (cols: [h | x])
    const float* __restrict__ bias,
    u32* __restrict__ prog,
    u32* __restrict__ hF, u32* __restrict__ hA,   // own-layer h rings
    u32* __restrict__ xF, u32* __restrict__ xA,   // hs0 rings
    float* __restrict__ out,
    u16* A_lds, float* D_lds, volatile int* mode_p)
{
    constexpr int K = 256 + KX;
    constexpr int NT = K / 32;
    constexpr int LDA = K + 8;
    constexpr int ABUF = 16 * LDA;

    const int tid = threadIdx.x;
    const int wave = tid >> 6;
    const int lane = tid & 63;
    const int g = lane >> 4;
    const int n = lane & 15;

    // ---- weights -> register B-fragments (two n-tiles per wave) ----
    const int a_gate = n >> 2, dd = n & 3;
    const int wrow0 = a_gate * 256 + q * 64 + 8 * wave + dd;
    const int wrow1 = wrow0 + 4;
    bf16x8 wf0[NT], wf1[NT];
    {
        const float* r0 = W + (long)wrow0 * K;
        const float* r1 = W + (long)wrow1 * K;
#pragma unroll
        for (int kt = 0; kt < NT; ++kt) {
            const float* p0 = r0 + kt * 32 + g * 8;
            const float* p1 = r1 + kt * 32 + g * 8;
            float4 a = *(const float4*)p0, b = *(const float4*)(p0 + 4);
            float4 c = *(const float4*)p1, d = *(const float4*)(p1 + 4);
            bf16x8 f0, f1;
            f0[0]=(__bf16)a.x; f0[1]=(__bf16)a.y; f0[2]=(__bf16)a.z; f0[3]=(__bf16)a.w;
            f0[4]=(__bf16)b.x; f0[5]=(__bf16)b.y; f0[6]=(__bf16)b.z; f0[7]=(__bf16)b.w;
            f1[0]=(__bf16)c.x; f1[1]=(__bf16)c.y; f1[2]=(__bf16)c.z; f1[3]=(__bf16)c.w;
            f1[4]=(__bf16)d.x; f1[5]=(__bf16)d.y; f1[6]=(__bf16)d.z; f1[7]=(__bf16)d.w;
            wf0[kt] = f0; wf1[kt] = f1;
        }
    }
    const float bias0 = bias[wrow0];
    const float bias1 = bias[wrow1];

    const int eb = lane & 15;
    const int edd = lane >> 4;
    float c0 = 0.f, c1 = 0.f;
    const int pub_base = (grp * 16 + eb) * 256 + q * 64 + 8 * wave + edd;

    const int sb = tid >> 5;
    const int seg = tid & 31;
    const int con_base = (grp * 16 + sb) * 256 + seg * 8;

    auto stage_x = [&](int t) {
        if constexpr (L0) {
            const float* p = xf + ((long)(grp * 16 + sb) * T_STEPS + t) * 128 + seg * 4;
            float4 v = *(const float4*)p;
            u16x4 h; h[0]=f2bf(v.x); h[1]=f2bf(v.y); h[2]=f2bf(v.z); h[3]=f2bf(v.w);
            *(u16x4*)&A_lds[(t & 1) * ABUF + sb * LDA + 256 + seg * 4] = h;
        }
    };
    auto stage_xr = [&](int t) {  // L1: validated read of hs0 tag t+1
        if constexpr (!L0) {
            const u32 xt = (u32)(t + 1);
            const size_t off = (size_t)((t + 1) & (XR - 1)) * XSLOT + con_base;
            u32* pF = xF + off; const u32* pA = xA + off;
            u32 tw[8]; int m = *mode_p; int gu = 0;
            for (;;) {
                if (m) {
#pragma unroll
                    for (int j = 0; j < 8; ++j) tw[j] = l2rmw(pF + j);
                } else {
#pragma unroll
                    for (int j = 0; j < 8; ++j) tw[j] = gload(pA + j);
                }
                u32 bad = 0;
#pragma unroll
                for (int j = 0; j < 8; ++j) bad |= (tw[j] >> 16) ^ xt;
                if (!bad) break;
                ++gu;
                if (m && gu == 256) { m = 0; *mode_p = 0; }
                if (gu > (1 << 17)) break;
                if ((gu & 3) == 3) __builtin_amdgcn_s_sleep(1);
            }
            u32x4 w;
#pragma unroll
            for (int j = 0; j < 4; ++j) w[j] = (tw[2 * j] & 0xffffu) | (tw[2 * j + 1] << 16);
            u32* Arow = (u32*)(A_lds + (t & 1) * ABUF + sb * LDA);
            *(u32x4*)&Arow[128 + seg * 4] = w;
        }
    };

    // seed h(0)=0 (tag 0) into the FAST ring from this block's own slice, so
    // the local-L2 copy is correct regardless of stale lines from past replays
    {
        u32* f0 = hF + pub_base;   // slot 0
        fpub(f0, 0u); fpub(f0 + 4, 0u);
    }

    if constexpr (L0) stage_x(0); else stage_xr(-1 + 0), stage_xr(0);

    for (int s = 0; s < T_STEPS; ++s) {
        u16* Abuf = A_lds + (s & 1) * ABUF;

        // ---- L0 backpressure on hs0 ring (agent; rare) ----
        if constexpr (L0) {
            if ((s & 15) == 0 && s >= 16 && tid < GQ) {
                const u32 need = (u32)(s - 12);
                const u32* pp = prog + (grp * GQ + tid) * 16;
                int gu = 0;
                while (gload(pp) < need && ++gu < (1 << 17)) {}
            }
        }

        // ---- probe: 4 threads watch 1 representative word per producer ----
        if (tid < GQ) {
            const size_t roff = (size_t)(s & (HR - 1)) * HSLOT
                              + (size_t)(grp * 16 + 15) * 256 + tid * 64 + 63;
            u32* rF = hF + roff; const u32* rA = hA + roff;
            int m = *mode_p; int gu = 0;
            for (;;) {
                u32 v = m ? l2rmw(rF) : gload(rA);
                if ((v >> 16) == (u32)s) break;
                ++gu;
                if (m && gu == 4096) { m = 0; *mode_p = 0; }
                if (gu > (1 << 17)) break;
            }
        }
        __syncthreads();

        // ---- validated full read of h(s) + LDS stage ----
        {
            const size_t off = (size_t)(s & (HR - 1)) * HSLOT + con_base;
            u32* pF = hF + off; const u32* pA = hA + off;
            u32 tw[8]; int m = *mode_p; int gu = 0;
            for (;;) {
                if (m) {
#pragma unroll
                    for (int j = 0; j < 8; ++j) tw[j] = l2rmw(pF + j);
                } else {
#pragma unroll
                    for (int j = 0; j < 8; ++j) tw[j] = gload(pA + j);
                }
                u32 bad = 0;
#pragma unroll
                for (int j = 0; j < 8; ++j) bad |= (tw[j] >> 16) ^ (u32)s;
                if (!bad) break;
                ++gu;
                if (m && gu == 64) { m = 0; *mode_p = 0; }
                if (gu > (1 << 16)) break;
            }
            u32x4 w;
#pragma unroll
            for (int j = 0; j < 4; ++j) w[j] = (tw[2 * j] & 0xffffu) | (tw[2 * j + 1] << 16);
            u32* Arow = (u32*)(Abuf + sb * LDA);
            *(u32x4*)&Arow[seg * 4] = w;
        }
        __syncthreads();

        // ---- MFMA: two n-tiles, 2 chains each ----
        f32x4 c00 = {bias0, bias0, bias0, bias0}, c01 = {0.f, 0.f, 0.f, 0.f};
        f32x4 c10 = {bias1, bias1, bias1, bias1}, c11 = {0.f, 0.f, 0.f, 0.f};
#pragma unroll
        for (int kt = 0; kt < NT; ++kt) {
            bf16x8 af = __builtin_bit_cast(
                bf16x8, *(const u16x8*)&Abuf[n * LDA + kt * 32 + g * 8]);
            if (kt & 1) {
                c01 = __builtin_amdgcn_mfma_f32_16x16x32_bf16(af, wf0[kt], c01, 0, 0, 0);
                c11 = __builtin_amdgcn_mfma_f32_16x16x32_bf16(af, wf1[kt], c11, 0, 0, 0);
            } else {
                c00 = __builtin_amdgcn_mfma_f32_16x16x32_bf16(af, wf0[kt], c00, 0, 0, 0);
                c10 = __builtin_amdgcn_mfma_f32_16x16x32_bf16(af, wf1[kt], c10, 0, 0, 0);
            }
        }
        f32x4 acc0 = c00 + c01, acc1 = c10 + c11;

        // ---- regroup via wave-local LDS ----
#pragma unroll
        for (int r = 0; r < 4; ++r) {
            D_lds[wave * 544 + n * 17 + g * 4 + r] = acc0[r];
            D_lds[wave * 544 + 272 + n * 17 + g * 4 + r] = acc1[r];
        }
        float ga0[4], ga1[4];
#pragma unroll
        for (int a = 0; a < 4; ++a) {
            ga0[a] = D_lds[wave * 544 + (a * 4 + edd) * 17 + eb];
            ga1[a] = D_lds[wave * 544 + 272 + (a * 4 + edd) * 17 + eb];
        }

        // ---- elementwise (gate order f,i,o,g) ----
        float h0, h1;
        {
            float fg = sigm(ga0[0]), ig = sigm(ga0[1]), og = sigm(ga0[2]), gg = tanh_(ga0[3]);
            c0 = fg * c0 + ig * gg; h0 = og * tanh_(c0);
            fg = sigm(ga1[0]); ig = sigm(ga1[1]); og = sigm(ga1[2]); gg = tanh_(ga1[3]);
            c1 = fg * c1 + ig * gg; h1 = og * tanh_(c1);
        }

        // ---- publish h(s+1): fast ring (local L2) + agent ring (MALL) ----
        const u32 t0 = ((u32)(s + 1) << 16) | f2bf(h0);
        const u32 t1 = ((u32)(s + 1) << 16) | f2bf(h1);
        {
            const size_t hoff = (size_t)((s + 1) & (HR - 1)) * HSLOT + pub_base;
            fpub(hF + hoff, t0);  fpub(hF + hoff + 4, t1);
            gstore(hA + hoff, t0); gstore(hA + hoff + 4, t1);
            if constexpr (L0) {
                const size_t xoff = (size_t)((s + 1) & (XR - 1)) * XSLOT + pub_base;
                fpub(xF + xoff, t0);  fpub(xF + xoff + 4, t1);
                gstore(xA + xoff, t0); gstore(xA + xoff + 4, t1);
            }
        }

        if (s == T_STEPS - 1) {
            const int o1 = pub_base;
            if constexpr (L0) {
                out[16384 + o1] = h0;     out[16384 + o1 + 4] = h1;   // h_n[0]
                out[49152 + o1] = c0;     out[49152 + o1 + 4] = c1;   // c_n[0]
            } else {
                out[o1] = h0;             out[o1 + 4] = h1;           // h1T
                out[32768 + o1] = h0;     out[32768 + o1 + 4] = h1;   // h_n[1]
                out[65536 + o1] = c0;     out[65536 + o1 + 4] = c1;   // c_n[1]
            }
        }

        if constexpr (L0) {
            if (s + 1 < T_STEPS) stage_x(s + 1);  // guarded (t=512 OOB)
        } else {
            if (tid == 0) gstore(prog + (grp * GQ + q) * 16, (u32)(s + 1));
            if (s + 1 < T_STEPS) stage_xr(s + 1);
        }
    }
}

__global__ __launch_bounds__(512, 2) void lstm_fused(
    const float* __restrict__ xf,
    const float* __restrict__ W0, const float* __restrict__ b0,
    const float* __restrict__ W1, const float* __restrict__ b1,
    u32* __restrict__ fhs, u32* __restrict__ prog,
    u32* __restrict__ hA0, u32* __restrict__ hA1,
    u32* __restrict__ hF0, u32* __restrict__ hF1,
    u32* __restrict__ xA, u32* __restrict__ xF,
    float* __restrict__ out)
{
    const int bid = blockIdx.x;
    const int res = bid & 7;
    if (res >= 4) return;          // XCDs 4-7 idle: all 8 group members share
    const int grp = res;           // one XCD (bid%8 residue) in default mapping
    const int mem = bid >> 3;      // 0..7
    const int layer = mem >> 2;
    const int q = mem & 3;

    __shared__ u16 A_lds[2 * 16 * 520];
    __shared__ float D_lds[8 * 544];
    __shared__ int ok_sh[8];
    __shared__ volatile int mode_sh;

    // ---- empirical visibility handshake: test the EXACT primitive pair ----
    if (threadIdx.x == 0)
        fpub(fhs + (size_t)bid * 16, 0xA5000000u | (u32)bid);
    const int nprod = layer ? 8 : 4;
    if ((int)threadIdx.x < nprod) {
        const int t = threadIdx.x;
        const int pl = layer ? (t < 4 ? 1 : 0) : 0;
        const int pbid = grp + 8 * (pl * 4 + (t & 3));
        const u32 want = 0xA5000000u | (u32)pbid;
        u32* pp = fhs + (size_t)pbid * 16;
        int seen = 0;
        for (int gu = 0; gu < (1 << 13); ++gu)
            if (l2rmw(pp) == want) { seen = 1; break; }
        ok_sh[t] = seen;
    }
    __syncthreads();
    if (threadIdx.x == 0) {
        int m = 1;
        for (int i = 0; i < nprod; ++i) m &= ok_sh[i];
        mode_sh = m;
    }
    __syncthreads();

    if (layer == 0) {
        lstm_body<128, true >(grp, q, xf, W0, b0, prog, hF0, hA0, xF, xA, out,
                              A_lds, D_lds, &mode_sh);
    } else {
        lstm_body<256, false>(grp, q, nullptr, W1, b1, prog, hF1, hA1, xF, xA, out,
                              A_lds, D_lds, &mode_sh);
    }
}

extern "C" void kernel_launch(void* const* d_in, const int* in_sizes, int n_in,
                              void* d_out, int out_size, void* d_ws, size_t ws_size,
                              hipStream_t stream) {
    (void)in_sizes; (void)n_in; (void)out_size;
    const float* x  = (const float*)d_in[0];
    const float* W0 = (const float*)d_in[1];
    const float* b0 = (const float*)d_in[2];
    const float* W1 = (const float*)d_in[3];
    const float* b1 = (const float*)d_in[4];
    float* out = (float*)d_out;

    char* ws = (char*)d_ws;
    u32* fhs = (u32*)(ws + FHS_OFF);
    u32* prog = (u32*)(ws + PROG_OFF);
    u32* hA0 = (u32*)(ws + HA0_OFF);
    u32* hA1 = (u32*)(ws + HA1_OFF);
    u32* hF0 = (u32*)(ws + HF0_OFF);
    u32* hF1 = (u32*)(ws + HF1_OFF);
    u32* xA = (u32*)(ws + XA_OFF);
    u32* xF = (u32*)(ws + XF_OFF);

    if (ws_size < WS_NEEDED) return;

    // Zero tokens + rings each call (agent-visible init; fast-ring slot0 is
    // additionally self-seeded in-kernel since memset can't reach stale L2 lines)
    hipMemsetAsync(d_ws, 0, WS_NEEDED, stream);

    lstm_fused<<<64, 512, 0, stream>>>(x, W0, b0, W1, b1, fhs, prog,
                                       hA0, hA1, hF0, hF1, xA, xF, out);
}